// Round 7
// baseline (11319.120 us; speedup 1.0000x reference)
//
#include <hip/hip_runtime.h>
#include <cstdint>
#include <cstddef>

typedef _Float16 f16;
typedef _Float16 f16x8 __attribute__((ext_vector_type(8)));
typedef _Float16 f16x4v __attribute__((ext_vector_type(4)));
typedef float f32x4 __attribute__((ext_vector_type(4)));
typedef unsigned uint2v __attribute__((ext_vector_type(2)));
typedef unsigned uint4v __attribute__((ext_vector_type(4)));   // asm-friendly 16B vector

#define TT 2048
#define BB 16
#define DD 1024
#define MM (TT*BB)
#define LDST 40   // padded LDS row stride (halves) to break bank conflicts
#define NREC (BB*DD/4)   // records per h buffer: one per (b, 4-elem d-chunk)

// ---------------- f32 -> f16 convert ----------------
__global__ void cvt_kernel(const float* __restrict__ in, f16* __restrict__ out, int n4){
  int stride = gridDim.x * blockDim.x;
  for (int j = blockIdx.x*blockDim.x + threadIdx.x; j < n4; j += stride){
    float4 v = ((const float4*)in)[j];
    f16x4v o;
    o[0]=(f16)v.x; o[1]=(f16)v.y; o[2]=(f16)v.z; o[3]=(f16)v.w;
    ((f16x4v*)out)[j] = o;
  }
}

// ---------------- recurrence init: h0 -> tagged records (tag=0) in buffer 0 ----------------
// Plain stores OK: kernel-end implicit device release flushes L2 (verified rounds 2-5:
// init's plain hbuf writes were read by rec's sc0sc1 loads at t=0 and passed).
__global__ void init_rec_kernel(const float* __restrict__ h0, uint4v* __restrict__ recs){
  int tid = blockIdx.x*blockDim.x + threadIdx.x;
  if (tid < NREC){
    int b = tid >> 8, c = tid & 255;          // record (b, chunk c) = h0[b][4c..4c+4]
    float4 v = *(const float4*)(h0 + (size_t)b*DD + c*4);
    f16x4v h4;
    h4[0]=(f16)v.x; h4[1]=(f16)v.y; h4[2]=(f16)v.z; h4[3]=(f16)v.w;
    uint2v hb = __builtin_bit_cast(uint2v, h4);
    uint4v rec = {hb[0], hb[1], 0u, 0u};
    recs[tid] = rec;
  }
}

// ---------------- 128x128 f16 MFMA GEMM, B given as [N,K] (i.e. W[e,d]) ----------------
// out[row,col] = sum_k A[row,k] * Bw[col,k]  (+ epilogue)
__global__ __launch_bounds__(256)
void gemm_f16_kernel(const f16* __restrict__ A, const f16* __restrict__ Bw,
                     float* __restrict__ out32, f16* __restrict__ out16,
                     const float* __restrict__ vec1, const float* __restrict__ vec2,
                     const f16* __restrict__ gxin, int epi)
{
  __shared__ f16 As[128*LDST];
  __shared__ f16 Bs[128*LDST];
  const int K = DD;
  int tid = threadIdx.x;
  int l = tid & 63, w = tid >> 6;
  int wr = w >> 1, wc = w & 1;
  int bm = blockIdx.x, bn = blockIdx.y;

  f32x4 acc[4][4];
  #pragma unroll
  for (int i=0;i<4;++i)
    #pragma unroll
    for (int j=0;j<4;++j)
      acc[i][j] = (f32x4){0.f,0.f,0.f,0.f};

  const int r0 = tid >> 2;   // 0..63
  const int q  = tid & 3;    // 0..3 (16B chunk within a 64B row)

  for (int kt = 0; kt < K/32; ++kt){
    __syncthreads();
    #pragma unroll
    for (int hh=0; hh<2; ++hh){
      int row = hh*64 + r0;
      uint4 va = *(const uint4*)(A  + (size_t)(bm*128+row)*K + kt*32 + q*8);
      uint4 vb = *(const uint4*)(Bw + (size_t)(bn*128+row)*K + kt*32 + q*8);
      *(uint4*)(As + row*LDST + q*8) = va;
      *(uint4*)(Bs + row*LDST + q*8) = vb;
    }
    __syncthreads();
    int lr = l & 15, kg = (l >> 4) * 8;
    f16x8 af[4], bf[4];
    #pragma unroll
    for (int i=0;i<4;++i){
      af[i] = *(const f16x8*)(As + (wr*64 + i*16 + lr)*LDST + kg);
      bf[i] = *(const f16x8*)(Bs + (wc*64 + i*16 + lr)*LDST + kg);
    }
    #pragma unroll
    for (int i=0;i<4;++i)
      #pragma unroll
      for (int j=0;j<4;++j)
        acc[i][j] = __builtin_amdgcn_mfma_f32_16x16x32_f16(af[i], bf[j], acc[i][j], 0,0,0);
  }

  int lr = l & 15, lh = l >> 4;
  #pragma unroll
  for (int i=0;i<4;++i){
    #pragma unroll
    for (int j=0;j<4;++j){
      #pragma unroll
      for (int r=0;r<4;++r){
        int row = bm*128 + wr*64 + i*16 + lh*4 + r;
        int col = bn*128 + wc*64 + j*16 + lr;
        float v = acc[i][j][r];
        size_t off = (size_t)row*DD + col;
        if (epi == 0){                       // wx = x@Wx^T + bias  (f32, stashed in d_out)
          out32[off] = v + vec1[col];
        } else if (epi == 1){                // alpha = exp(-softplus(pre+b_delta)*exp(-exp(A)))
          float pre = v + vec1[col];
          float sp  = (pre > 20.f) ? pre : log1pf(expf(pre));
          float decay = expf(-expf(vec2[col]));
          out32[off] = expf(-sp*decay);
        } else if (epi == 2){                // gx = x@Wgx^T + b_gate  (f16)
          out16[off] = (f16)(v + vec1[col]);
        } else {                             // out = h * silu(acc + gx)
          float g = v + (float)gxin[off];
          float hval = (float)A[off];        // A == h_out_f16
          out32[off] = hval * g / (1.f + expf(-g));
        }
      }
    }
  }
}

// ---------------- recurrence: 64 WGs, slice of 16 e-rows each, seqlock-tagged h ----------------
// h record (16B, one global_store_dwordx4 => atomic): {f16x4 h, uint tag, uint pad}.
// recs[s][b][c]: s = step parity, b = batch, c = d/4 chunk. Producer of h_{t+1} writes
// tag t+1 into buffer (t+1)&1, fire-and-forget (tag travels WITH data -> no drain, no flag).
// Consumer at step t polls its 16 records in buffer t&1 until all tags == t.
__global__ __launch_bounds__(256)
void rec_kernel(const f16* __restrict__ Rf, const float* __restrict__ wx,
                const float* __restrict__ alpha, const float* __restrict__ h0,
                uint4v* __restrict__ recs, f16* __restrict__ hout)
{
  __shared__ f16  Rlds[32*64*8];   // 32KB, frag-ordered: chunk c = kt*64+lane, 8 halves each
  __shared__ float plds[3*64*4];   // waves 1-3 partial C

  int tid = threadIdx.x;
  int l = tid & 63, w = tid >> 6;
  int j = blockIdx.x;              // slice id 0..63
  int e0 = j * 16;

  // Load R slice into LDS in MFMA-fragment order (one-time).
  for (int it=0; it<8; ++it){
    int c = it*256 + tid;          // 0..2047
    int lane = c & 63, kt = c >> 6;
    int e = e0 + (lane & 15);
    int d = kt*32 + (lane >> 4)*8;
    uint4 v = *(const uint4*)(Rf + (size_t)e*DD + d);
    *(uint4*)(Rlds + (size_t)c*8) = v;
  }

  // wave0 per-lane output mapping: lane l owns (b = l&15, e = e0 + rr0..rr0+3)
  int b = l & 15, rr0 = (l >> 4) * 4;
  float4 hstate = {0.f,0.f,0.f,0.f};
  if (w == 0)
    hstate = *(const float4*)(h0 + (size_t)b*DD + e0 + rr0);

  // consumer record indices: wave w lane l needs h[b][d0..d0+8), d0 = (w*8+kk)*32 + (l>>4)*8
  // -> chunks c0 = d0/4 and c0+1 (adjacent 32B). Base index (excl. kk term):
  const int cbase = (l & 15)*256 + (l >> 4)*2;   // b*256 + (l>>4)*2
  __syncthreads();

  for (int t = 0; t < TT; ++t){
    const uint4v* rb = recs + (size_t)(t & 1) * NREC;
    unsigned expect = (unsigned)t;

    // ---- poll own 16 records until fresh (discovery == data load, one LLC hop) ----
    uint4v r0[8], r1[8];
    int ok = 0;
    for (int it = 0; it < 200000 && !ok; ++it){
      if (it) __builtin_amdgcn_s_sleep(1);
      #pragma unroll
      for (int kk=0; kk<8; ++kk){
        const uint4v* p = rb + cbase + (w*8 + kk)*8;   // chunk c0 = (w*8+kk)*8 + (l>>4)*2
        asm volatile("global_load_dwordx4 %0, %1, off sc0 sc1"
                     : "=v"(r0[kk]) : "v"(p) : "memory");
        asm volatile("global_load_dwordx4 %0, %1, off sc0 sc1"
                     : "=v"(r1[kk]) : "v"(p+1) : "memory");
      }
      asm volatile("s_waitcnt vmcnt(0)" ::: "memory");
      __builtin_amdgcn_sched_barrier(0);
      unsigned bad = 0;
      #pragma unroll
      for (int kk=0; kk<8; ++kk)
        bad |= (r0[kk][2] ^ expect) | (r1[kk][2] ^ expect);
      ok = (__ballot(bad != 0) == 0ull);
    }

    // wx/alpha for this step: plain loads AFTER the poll (complete under MFMA+reduce,
    // consumed in epilogue; compiler manages waitcnt -> correct by construction)
    f32x4 wxv = (f32x4){0,0,0,0}, alv = (f32x4){0,0,0,0};
    size_t off4 = ((size_t)t*BB + b)*DD + e0 + rr0;
    if (w == 0){
      wxv = *(const f32x4*)(wx + off4);
      alv = *(const f32x4*)(alpha + off4);
    }

    f32x4 acc = (f32x4){0.f,0.f,0.f,0.f};
    #pragma unroll
    for (int kk=0; kk<8; ++kk){
      int kt = w*8 + kk;
      uint4v packed = {r0[kk][0], r0[kk][1], r1[kk][0], r1[kk][1]};
      f16x8 bfrag = __builtin_bit_cast(f16x8, packed);
      f16x8 a = *(const f16x8*)(Rlds + ((size_t)kt*64 + l)*8);
      acc = __builtin_amdgcn_mfma_f32_16x16x32_f16(a, bfrag, acc, 0, 0, 0);
    }
    if (w) *(f32x4*)(plds + ((size_t)(w-1)*64 + l)*4) = acc;
    __syncthreads();   // ONE barrier/step: plds visible to wave0. Waves 1-3 can't
                       // overwrite plds at t+1 before wave0's reduce here: their t+1
                       // poll needs this WG's tag t+1, published only after the reduce.

    if (w == 0){
      f32x4 v = acc;
      #pragma unroll
      for (int q=0;q<3;++q)
        v += *(const f32x4*)(plds + ((size_t)q*64 + l)*4);

      f16x4v h4;
      float hs[4] = {hstate.x, hstate.y, hstate.z, hstate.w};
      #pragma unroll
      for (int r=0;r<4;++r){
        float z = v[r] + wxv[r];
        float cand = tanhf(z);
        float hn = alv[r]*hs[r] + (1.f - alv[r])*cand;
        hs[r] = hn;
        h4[r] = (f16)hn;
      }
      hstate = (float4){hs[0], hs[1], hs[2], hs[3]};

      // tagged record store: data+tag in ONE 16B coherent store, fire-and-forget
      uint2v hb = __builtin_bit_cast(uint2v, h4);
      uint4v rec = {hb[0], hb[1], (unsigned)(t+1), 0u};
      uint4v* rp = recs + (size_t)((t+1) & 1)*NREC + (size_t)b*256 + (e0 + rr0)/4;
      asm volatile("global_store_dwordx4 %0, %1, off sc0 sc1"
                   :: "v"(rp), "v"(rec) : "memory");
      // hout store off the critical path (plain cached store)
      *(f16x4v*)(hout + off4) = h4;
    }
  }
}

// ---------------- host launcher ----------------
extern "C" void kernel_launch(void* const* d_in, const int* in_sizes, int n_in,
                              void* d_out, int out_size, void* d_ws, size_t ws_size,
                              hipStream_t stream)
{
  const float* x    = (const float*)d_in[0];
  const float* h0   = (const float*)d_in[1];
  const float* Wx   = (const float*)d_in[2];
  const float* R    = (const float*)d_in[3];
  const float* bias = (const float*)d_in[4];
  const float* Wd   = (const float*)d_in[5];
  const float* bd   = (const float*)d_in[6];
  const float* Aar  = (const float*)d_in[7];
  const float* Wgx  = (const float*)d_in[8];
  const float* Wgh  = (const float*)d_in[9];
  const float* bg   = (const float*)d_in[10];
  float* out = (float*)d_out;

  char* ws = (char*)d_ws;
  size_t off = 0;
  auto carve = [&](size_t bytes) -> void* {
    void* p = ws + off;
    off += (bytes + 255) & ~(size_t)255;
    return p;
  };
  f16* x16    = (f16*)carve((size_t)MM*DD*2);
  f16* Wx16   = (f16*)carve((size_t)DD*DD*2);
  f16* Wd16   = (f16*)carve((size_t)DD*DD*2);
  f16* Wgx16  = (f16*)carve((size_t)DD*DD*2);
  f16* Wgh16  = (f16*)carve((size_t)DD*DD*2);
  f16* R16    = (f16*)carve((size_t)DD*DD*2);
  float* alphaB = (float*)carve((size_t)MM*DD*4);
  f16* gx16   = (f16*)carve((size_t)MM*DD*2);
  f16* hout16 = (f16*)carve((size_t)MM*DD*2);
  uint4v* recs = (uint4v*)carve((size_t)2*NREC*16);
  if (off > ws_size) return;  // ws too small: leave d_out poisoned (visible failure)

  float* wxbuf = out;  // stash wx in d_out; final GEMM overwrites it

  cvt_kernel<<<1024, 256, 0, stream>>>(x,   x16,   MM*DD/4);
  cvt_kernel<<<256,  256, 0, stream>>>(Wx,  Wx16,  DD*DD/4);
  cvt_kernel<<<256,  256, 0, stream>>>(Wd,  Wd16,  DD*DD/4);
  cvt_kernel<<<256,  256, 0, stream>>>(Wgx, Wgx16, DD*DD/4);
  cvt_kernel<<<256,  256, 0, stream>>>(Wgh, Wgh16, DD*DD/4);
  cvt_kernel<<<256,  256, 0, stream>>>(R,   R16,   DD*DD/4);
  init_rec_kernel<<<64, 256, 0, stream>>>(h0, recs);

  dim3 gg(MM/128, DD/128);
  gemm_f16_kernel<<<gg, 256, 0, stream>>>(x16, Wx16,  wxbuf,  nullptr, bias, nullptr, nullptr, 0);
  gemm_f16_kernel<<<gg, 256, 0, stream>>>(x16, Wd16,  alphaB, nullptr, bd,   Aar,     nullptr, 1);
  gemm_f16_kernel<<<gg, 256, 0, stream>>>(x16, Wgx16, nullptr, gx16,   bg,   nullptr, nullptr, 2);

  rec_kernel<<<64, 256, 0, stream>>>(R16, wxbuf, alphaB, h0, recs, hout16);

  gemm_f16_kernel<<<gg, 256, 0, stream>>>(hout16, Wgh16, out, nullptr, nullptr, nullptr, gx16, 3);
}

// Round 8
// 7577.181 us; speedup vs baseline: 1.4938x; 1.4938x over previous
//
#include <hip/hip_runtime.h>
#include <cstdint>
#include <cstddef>

typedef _Float16 f16;
typedef _Float16 f16x8 __attribute__((ext_vector_type(8)));
typedef _Float16 f16x4v __attribute__((ext_vector_type(4)));
typedef float f32x4 __attribute__((ext_vector_type(4)));
typedef unsigned uint2v __attribute__((ext_vector_type(2)));

#define TT 2048
#define BB 16
#define DD 1024
#define MM (TT*BB)
#define LDST 40   // padded LDS row stride (halves) to break bank conflicts
#define FPAD 16   // flag padding: one flag per 64B line

// ---------------- f32 -> f16 convert ----------------
__global__ void cvt_kernel(const float* __restrict__ in, f16* __restrict__ out, int n4){
  int stride = gridDim.x * blockDim.x;
  for (int j = blockIdx.x*blockDim.x + threadIdx.x; j < n4; j += stride){
    float4 v = ((const float4*)in)[j];
    f16x4v o;
    o[0]=(f16)v.x; o[1]=(f16)v.y; o[2]=(f16)v.z; o[3]=(f16)v.w;
    ((f16x4v*)out)[j] = o;
  }
}

// ---------------- recurrence init: zero flags, h0 -> hbuf[0] ----------------
__global__ void init_rec_kernel(const float* __restrict__ h0, f16* __restrict__ hbuf,
                                unsigned* __restrict__ flags){
  int tid = blockIdx.x*blockDim.x + threadIdx.x;
  if (tid < 64*FPAD) flags[tid] = 0u;
  if (tid < BB*DD) hbuf[tid] = (f16)h0[tid];   // hbuf[0][b][e], same layout as h0
}

// ---------------- 128x128 f16 MFMA GEMM, B given as [N,K] (i.e. W[e,d]) ----------------
// out[row,col] = sum_k A[row,k] * Bw[col,k]  (+ epilogue)
__global__ __launch_bounds__(256)
void gemm_f16_kernel(const f16* __restrict__ A, const f16* __restrict__ Bw,
                     float* __restrict__ out32, f16* __restrict__ out16,
                     const float* __restrict__ vec1, const float* __restrict__ vec2,
                     const f16* __restrict__ gxin, int epi)
{
  __shared__ f16 As[128*LDST];
  __shared__ f16 Bs[128*LDST];
  const int K = DD;
  int tid = threadIdx.x;
  int l = tid & 63, w = tid >> 6;
  int wr = w >> 1, wc = w & 1;
  int bm = blockIdx.x, bn = blockIdx.y;

  f32x4 acc[4][4];
  #pragma unroll
  for (int i=0;i<4;++i)
    #pragma unroll
    for (int j=0;j<4;++j)
      acc[i][j] = (f32x4){0.f,0.f,0.f,0.f};

  const int r0 = tid >> 2;   // 0..63
  const int q  = tid & 3;    // 0..3 (16B chunk within a 64B row)

  for (int kt = 0; kt < K/32; ++kt){
    __syncthreads();
    #pragma unroll
    for (int hh=0; hh<2; ++hh){
      int row = hh*64 + r0;
      uint4 va = *(const uint4*)(A  + (size_t)(bm*128+row)*K + kt*32 + q*8);
      uint4 vb = *(const uint4*)(Bw + (size_t)(bn*128+row)*K + kt*32 + q*8);
      *(uint4*)(As + row*LDST + q*8) = va;
      *(uint4*)(Bs + row*LDST + q*8) = vb;
    }
    __syncthreads();
    int lr = l & 15, kg = (l >> 4) * 8;
    f16x8 af[4], bf[4];
    #pragma unroll
    for (int i=0;i<4;++i){
      af[i] = *(const f16x8*)(As + (wr*64 + i*16 + lr)*LDST + kg);
      bf[i] = *(const f16x8*)(Bs + (wc*64 + i*16 + lr)*LDST + kg);
    }
    #pragma unroll
    for (int i=0;i<4;++i)
      #pragma unroll
      for (int j=0;j<4;++j)
        acc[i][j] = __builtin_amdgcn_mfma_f32_16x16x32_f16(af[i], bf[j], acc[i][j], 0,0,0);
  }

  int lr = l & 15, lh = l >> 4;
  #pragma unroll
  for (int i=0;i<4;++i){
    #pragma unroll
    for (int j=0;j<4;++j){
      #pragma unroll
      for (int r=0;r<4;++r){
        int row = bm*128 + wr*64 + i*16 + lh*4 + r;
        int col = bn*128 + wc*64 + j*16 + lr;
        float v = acc[i][j][r];
        size_t off = (size_t)row*DD + col;
        if (epi == 0){                       // wx = x@Wx^T + bias  (f32, stashed in d_out)
          out32[off] = v + vec1[col];
        } else if (epi == 1){                // alpha = exp(-softplus(pre+b_delta)*exp(-exp(A)))
          float pre = v + vec1[col];
          float sp  = (pre > 20.f) ? pre : log1pf(expf(pre));
          float decay = expf(-expf(vec2[col]));
          out32[off] = expf(-sp*decay);
        } else if (epi == 2){                // gx = x@Wgx^T + b_gate  (f16)
          out16[off] = (f16)(v + vec1[col]);
        } else {                             // out = h * silu(acc + gx)
          float g = v + (float)gxin[off];
          float hval = (float)A[off];        // A == h_out_f16
          out32[off] = hval * g / (1.f + expf(-g));
        }
      }
    }
  }
}

// ---------------- recurrence: 64 autonomous single-wave WGs, 16 e-rows full-K each ----------
// No __syncthreads in the step loop, no cross-wave reduce: each wave computes its 16x16
// output tile over the FULL K=1024 (32 MFMAs), does the pointwise epilogue itself, then:
//   release: 64x8B coherent stores (1/lane) -> s_waitcnt vmcnt(0) -> lane0 flag store (AGENT)
//   acquire: lane l polls flags[l*FPAD] until all >= t (ballot) -> coherent h loads
__global__ __launch_bounds__(64)
void rec_kernel(const f16* __restrict__ Rf, const float* __restrict__ wx,
                const float* __restrict__ alpha, const float* __restrict__ h0,
                f16* __restrict__ hbuf, f16* __restrict__ hout,
                unsigned* __restrict__ flags)
{
  __shared__ f16 Rlds[32*64*8];   // 32KB, frag-ordered: chunk c = kt*64+lane, 8 halves each

  int l = threadIdx.x;             // 0..63 (one wave per WG)
  int j = blockIdx.x;              // slice id 0..63
  int e0 = j * 16;

  // Load R slice into LDS in MFMA-fragment order (one-time).
  #pragma unroll
  for (int kt=0; kt<32; ++kt){
    int e = e0 + (l & 15);
    int d = kt*32 + (l >> 4)*8;
    *(uint4*)(Rlds + ((size_t)kt*64 + l)*8) = *(const uint4*)(Rf + (size_t)e*DD + d);
  }

  // per-lane output mapping (MFMA C layout): lane l owns (b = l&15, e = e0 + rr0..rr0+3)
  int b = l & 15, rr0 = (l >> 4) * 4;
  float4 hstate = *(const float4*)(h0 + (size_t)b*DD + e0 + rr0);
  __syncthreads();

  // wx/alpha for t=0 preloaded; inside the loop we prefetch t+1 under the MFMA work.
  f32x4 wxv = *(const f32x4*)(wx + (size_t)b*DD + e0 + rr0);
  f32x4 alv = *(const f32x4*)(alpha + (size_t)b*DD + e0 + rr0);

  for (int t = 0; t < TT; ++t){
    if (t > 0){
      const unsigned* fp = flags + l*FPAD;
      int guard = 0;
      unsigned long long notready = 1ull;
      while (notready && guard < 2000000){
        unsigned fv = __hip_atomic_load(fp, __ATOMIC_RELAXED, __HIP_MEMORY_SCOPE_AGENT);
        notready = __ballot(fv < (unsigned)t);
        ++guard;
        if (notready) __builtin_amdgcn_s_sleep(1);
      }
    }

    // coherent single-shot load of this lane's full h row-slice (bypass stale L1/L2)
    const f16* hb = hbuf + (size_t)(t & 1) * (BB*DD);
    f16x8 hfr[32];
    #pragma unroll
    for (int kt=0; kt<32; ++kt){
      const f16* hp = hb + (size_t)b*DD + kt*32 + (l >> 4)*8;
      asm volatile("global_load_dwordx4 %0, %1, off sc0 sc1"
                   : "=v"(hfr[kt]) : "v"(hp) : "memory");
    }
    asm volatile("s_waitcnt vmcnt(0)" ::: "memory");
    __builtin_amdgcn_sched_barrier(0);

    // prefetch next step's wx/alpha (plain cached loads; complete under the MFMA loop;
    // compiler manages their waitcnt -> correct by construction)
    int tn = (t+1 < TT) ? (t+1) : t;
    size_t offn = ((size_t)tn*BB + b)*DD + e0 + rr0;
    f32x4 wxn = *(const f32x4*)(wx + offn);
    f32x4 aln = *(const f32x4*)(alpha + offn);

    // full-K MFMA: 32 x (ds_read_b128 + mfma 16x16x32), accumulate 16x16 tile
    f32x4 acc = (f32x4){0.f,0.f,0.f,0.f};
    #pragma unroll
    for (int kt=0; kt<32; ++kt){
      f16x8 a = *(const f16x8*)(Rlds + ((size_t)kt*64 + l)*8);
      acc = __builtin_amdgcn_mfma_f32_16x16x32_f16(a, hfr[kt], acc, 0, 0, 0);
    }

    // pointwise epilogue (same wave; no reduce, no barrier)
    f16x4v h4;
    float hs[4] = {hstate.x, hstate.y, hstate.z, hstate.w};
    #pragma unroll
    for (int r=0;r<4;++r){
      float z = acc[r] + wxv[r];
      float cand = tanhf(z);
      float hn = alv[r]*hs[r] + (1.f - alv[r])*cand;
      hs[r] = hn;
      h4[r] = (f16)hn;
    }
    hstate = (float4){hs[0], hs[1], hs[2], hs[3]};

    // release: one 8B coherent store per lane -> drain -> lane0 publishes
    f16* hw = hbuf + (size_t)((t+1) & 1) * (BB*DD) + (size_t)b*DD + e0 + rr0;
    uint2v hv = __builtin_bit_cast(uint2v, h4);
    asm volatile("global_store_dwordx2 %0, %1, off sc0 sc1"
                 :: "v"(hw), "v"(hv) : "memory");
    asm volatile("s_waitcnt vmcnt(0)" ::: "memory");
    if (l == 0)
      __hip_atomic_store(flags + j*FPAD, (unsigned)(t+1),
                         __ATOMIC_RELAXED, __HIP_MEMORY_SCOPE_AGENT);

    // off the critical path: plain hout store, rotate wx/alpha
    *(f16x4v*)(hout + ((size_t)t*BB + b)*DD + e0 + rr0) = h4;
    wxv = wxn; alv = aln;
  }
}

// ---------------- host launcher ----------------
extern "C" void kernel_launch(void* const* d_in, const int* in_sizes, int n_in,
                              void* d_out, int out_size, void* d_ws, size_t ws_size,
                              hipStream_t stream)
{
  const float* x    = (const float*)d_in[0];
  const float* h0   = (const float*)d_in[1];
  const float* Wx   = (const float*)d_in[2];
  const float* R    = (const float*)d_in[3];
  const float* bias = (const float*)d_in[4];
  const float* Wd   = (const float*)d_in[5];
  const float* bd   = (const float*)d_in[6];
  const float* Aar  = (const float*)d_in[7];
  const float* Wgx  = (const float*)d_in[8];
  const float* Wgh  = (const float*)d_in[9];
  const float* bg   = (const float*)d_in[10];
  float* out = (float*)d_out;

  char* ws = (char*)d_ws;
  size_t off = 0;
  auto carve = [&](size_t bytes) -> void* {
    void* p = ws + off;
    off += (bytes + 255) & ~(size_t)255;
    return p;
  };
  f16* x16    = (f16*)carve((size_t)MM*DD*2);
  f16* Wx16   = (f16*)carve((size_t)DD*DD*2);
  f16* Wd16   = (f16*)carve((size_t)DD*DD*2);
  f16* Wgx16  = (f16*)carve((size_t)DD*DD*2);
  f16* Wgh16  = (f16*)carve((size_t)DD*DD*2);
  f16* R16    = (f16*)carve((size_t)DD*DD*2);
  float* alphaB = (float*)carve((size_t)MM*DD*4);
  f16* gx16   = (f16*)carve((size_t)MM*DD*2);
  f16* hout16 = (f16*)carve((size_t)MM*DD*2);
  f16* hbuf   = (f16*)carve((size_t)2*BB*DD*2);
  unsigned* flags = (unsigned*)carve(64*FPAD*4);
  if (off > ws_size) return;  // ws too small: leave d_out poisoned (visible failure)

  float* wxbuf = out;  // stash wx in d_out; final GEMM overwrites it

  cvt_kernel<<<1024, 256, 0, stream>>>(x,   x16,   MM*DD/4);
  cvt_kernel<<<256,  256, 0, stream>>>(Wx,  Wx16,  DD*DD/4);
  cvt_kernel<<<256,  256, 0, stream>>>(Wd,  Wd16,  DD*DD/4);
  cvt_kernel<<<256,  256, 0, stream>>>(Wgx, Wgx16, DD*DD/4);
  cvt_kernel<<<256,  256, 0, stream>>>(Wgh, Wgh16, DD*DD/4);
  cvt_kernel<<<256,  256, 0, stream>>>(R,   R16,   DD*DD/4);
  init_rec_kernel<<<64, 256, 0, stream>>>(h0, hbuf, flags);

  dim3 gg(MM/128, DD/128);
  gemm_f16_kernel<<<gg, 256, 0, stream>>>(x16, Wx16,  wxbuf,  nullptr, bias, nullptr, nullptr, 0);
  gemm_f16_kernel<<<gg, 256, 0, stream>>>(x16, Wd16,  alphaB, nullptr, bd,   Aar,     nullptr, 1);
  gemm_f16_kernel<<<gg, 256, 0, stream>>>(x16, Wgx16, nullptr, gx16,   bg,   nullptr, nullptr, 2);

  rec_kernel<<<64, 64, 0, stream>>>(R16, wxbuf, alphaB, h0, hbuf, hout16, flags);

  gemm_f16_kernel<<<gg, 256, 0, stream>>>(hout16, Wgh16, out, nullptr, nullptr, nullptr, gx16, 3);
}

// Round 12
// 7279.695 us; speedup vs baseline: 1.5549x; 1.0409x over previous
//
#include <hip/hip_runtime.h>
#include <cstdint>
#include <cstddef>

typedef _Float16 f16;
typedef _Float16 f16x8 __attribute__((ext_vector_type(8)));
typedef _Float16 f16x4v __attribute__((ext_vector_type(4)));
typedef float f32x4 __attribute__((ext_vector_type(4)));
typedef unsigned uint2v __attribute__((ext_vector_type(2)));

#define TT 2048
#define BB 16
#define DD 1024
#define MM (TT*BB)
#define LDST 40   // padded LDS row stride (halves) to break bank conflicts
#define FPAD 16   // flag padding: one flag per 64B line

// ---------------- f32 -> f16 convert (single buffer) ----------------
__global__ void cvt_kernel(const float* __restrict__ in, f16* __restrict__ out, int n4){
  int stride = gridDim.x * blockDim.x;
  for (int j = blockIdx.x*blockDim.x + threadIdx.x; j < n4; j += stride){
    float4 v = ((const float4*)in)[j];
    f16x4v o;
    o[0]=(f16)v.x; o[1]=(f16)v.y; o[2]=(f16)v.z; o[3]=(f16)v.w;
    ((f16x4v*)out)[j] = o;
  }
}

// ---------------- fused f32->f16 convert for the 5 DxD weights ----------------
__global__ void cvt5_kernel(const float* __restrict__ a0, const float* __restrict__ a1,
                            const float* __restrict__ a2, const float* __restrict__ a3,
                            const float* __restrict__ a4,
                            f16* __restrict__ o0, f16* __restrict__ o1,
                            f16* __restrict__ o2, f16* __restrict__ o3, f16* __restrict__ o4){
  const float* src[5] = {a0,a1,a2,a3,a4};
  f16* dst[5] = {o0,o1,o2,o3,o4};
  int which = blockIdx.y;
  const float* in = src[which];
  f16* out = dst[which];
  int j = blockIdx.x*blockDim.x + threadIdx.x;   // grid.x*256 == DD*DD/4 exactly
  float4 v = ((const float4*)in)[j];
  f16x4v o;
  o[0]=(f16)v.x; o[1]=(f16)v.y; o[2]=(f16)v.z; o[3]=(f16)v.w;
  ((f16x4v*)out)[j] = o;
}

// ---------------- recurrence init: zero flags, h0 -> hbuf[0] ----------------
__global__ void init_rec_kernel(const float* __restrict__ h0, f16* __restrict__ hbuf,
                                unsigned* __restrict__ flags){
  int tid = blockIdx.x*blockDim.x + threadIdx.x;
  if (tid < 64*FPAD) flags[tid] = 0u;
  if (tid < BB*DD) hbuf[tid] = (f16)h0[tid];   // hbuf[0][b][e], same layout as h0
}

// ---------------- 128x128 f16 MFMA GEMM, B given as [N,K] (i.e. W[e,d]) ----------------
// out[row,col] = sum_k A[row,k] * Bw[col,k]  (+ epilogue)
__global__ __launch_bounds__(256)
void gemm_f16_kernel(const f16* __restrict__ A, const f16* __restrict__ Bw,
                     float* __restrict__ out32, f16* __restrict__ out16,
                     const float* __restrict__ vec1, const float* __restrict__ vec2,
                     const f16* __restrict__ gxin, int epi)
{
  __shared__ f16 As[128*LDST];
  __shared__ f16 Bs[128*LDST];
  const int K = DD;
  int tid = threadIdx.x;
  int l = tid & 63, w = tid >> 6;
  int wr = w >> 1, wc = w & 1;
  int bm = blockIdx.x, bn = blockIdx.y;

  f32x4 acc[4][4];
  #pragma unroll
  for (int i=0;i<4;++i)
    #pragma unroll
    for (int j=0;j<4;++j)
      acc[i][j] = (f32x4){0.f,0.f,0.f,0.f};

  const int r0 = tid >> 2;   // 0..63
  const int q  = tid & 3;    // 0..3 (16B chunk within a 64B row)

  for (int kt = 0; kt < K/32; ++kt){
    __syncthreads();
    #pragma unroll
    for (int hh=0; hh<2; ++hh){
      int row = hh*64 + r0;
      uint4 va = *(const uint4*)(A  + (size_t)(bm*128+row)*K + kt*32 + q*8);
      uint4 vb = *(const uint4*)(Bw + (size_t)(bn*128+row)*K + kt*32 + q*8);
      *(uint4*)(As + row*LDST + q*8) = va;
      *(uint4*)(Bs + row*LDST + q*8) = vb;
    }
    __syncthreads();
    int lr = l & 15, kg = (l >> 4) * 8;
    f16x8 af[4], bf[4];
    #pragma unroll
    for (int i=0;i<4;++i){
      af[i] = *(const f16x8*)(As + (wr*64 + i*16 + lr)*LDST + kg);
      bf[i] = *(const f16x8*)(Bs + (wc*64 + i*16 + lr)*LDST + kg);
    }
    #pragma unroll
    for (int i=0;i<4;++i)
      #pragma unroll
      for (int j=0;j<4;++j)
        acc[i][j] = __builtin_amdgcn_mfma_f32_16x16x32_f16(af[i], bf[j], acc[i][j], 0,0,0);
  }

  int lr = l & 15, lh = l >> 4;
  #pragma unroll
  for (int i=0;i<4;++i){
    #pragma unroll
    for (int j=0;j<4;++j){
      #pragma unroll
      for (int r=0;r<4;++r){
        int row = bm*128 + wr*64 + i*16 + lh*4 + r;
        int col = bn*128 + wc*64 + j*16 + lr;
        float v = acc[i][j][r];
        size_t off = (size_t)row*DD + col;
        if (epi == 0){                       // wx = x@Wx^T + bias  -> f16
          out16[off] = (f16)(v + vec1[col]);
        } else if (epi == 1){                // alpha = exp(-softplus(pre+b_delta)*decay) -> f16
          float pre = v + vec1[col];
          float sp  = (pre > 20.f) ? pre : log1pf(expf(pre));
          float decay = expf(-expf(vec2[col]));
          out16[off] = (f16)expf(-sp*decay);
        } else if (epi == 2){                // gx = x@Wgx^T + b_gate  (f16)
          out16[off] = (f16)(v + vec1[col]);
        } else {                             // out = h * silu(acc + gx)
          float g = v + (float)gxin[off];
          float hval = (float)A[off];        // A == h_out_f16
          out32[off] = hval * g / (1.f + expf(-g));
        }
      }
    }
  }
}

// ---------------- recurrence: 64 autonomous single-wave WGs (round-8 protocol) ----------
// Proven protocol (R8, passed): release = 8B sc0sc1 store/lane -> vmcnt(0) -> lane0 flag
// store (AGENT atomic); acquire = lane l polls flags[l*FPAD] until all >= t (ballot) ->
// sc0sc1 h loads. New this round (within-step only): split vmcnt wait to overlap the
// h-load tail with the first half of the MFMA chain; wx/alpha read as f16.
__global__ __launch_bounds__(64)
void rec_kernel(const f16* __restrict__ Rf, const f16* __restrict__ wx,
                const f16* __restrict__ alpha, const float* __restrict__ h0,
                f16* __restrict__ hbuf, f16* __restrict__ hout,
                unsigned* __restrict__ flags)
{
  __shared__ f16 Rlds[32*64*8];   // 32KB, frag-ordered: chunk c = kt*64+lane, 8 halves each

  int l = threadIdx.x;             // 0..63 (one wave per WG)
  int j = blockIdx.x;              // slice id 0..63
  int e0 = j * 16;

  // Load R slice into LDS in MFMA-fragment order (one-time).
  #pragma unroll
  for (int kt=0; kt<32; ++kt){
    int e = e0 + (l & 15);
    int d = kt*32 + (l >> 4)*8;
    *(uint4*)(Rlds + ((size_t)kt*64 + l)*8) = *(const uint4*)(Rf + (size_t)e*DD + d);
  }

  // per-lane output mapping (MFMA C layout): lane l owns (b = l&15, e = e0 + rr0..rr0+3)
  int b = l & 15, rr0 = (l >> 4) * 4;
  float4 hstate = *(const float4*)(h0 + (size_t)b*DD + e0 + rr0);
  __syncthreads();

  // wx/alpha for t=0 preloaded (f16 -> f32); in-loop we prefetch t+1 under the MFMA work.
  f32x4 wxv, alv;
  {
    f16x4v wh = *(const f16x4v*)(wx + (size_t)b*DD + e0 + rr0);
    f16x4v ah = *(const f16x4v*)(alpha + (size_t)b*DD + e0 + rr0);
    #pragma unroll
    for (int r=0;r<4;++r){ wxv[r] = (float)wh[r]; alv[r] = (float)ah[r]; }
  }

  for (int t = 0; t < TT; ++t){
    if (t > 0){
      const unsigned* fp = flags + l*FPAD;
      int guard = 0;
      unsigned long long notready = 1ull;
      while (notready && guard < 2000000){
        unsigned fv = __hip_atomic_load(fp, __ATOMIC_RELAXED, __HIP_MEMORY_SCOPE_AGENT);
        notready = __ballot(fv < (unsigned)t);
        ++guard;
        if (notready) __builtin_amdgcn_s_sleep(1);
      }
    }

    // coherent single-shot load of this lane's full h K-slice (bypass stale caches)
    const f16* hb = hbuf + (size_t)(t & 1) * (BB*DD);
    f16x8 hfr[32];
    #pragma unroll
    for (int kt=0; kt<32; ++kt){
      const f16* hp = hb + (size_t)b*DD + kt*32 + (l >> 4)*8;
      asm volatile("global_load_dwordx4 %0, %1, off sc0 sc1"
                   : "=v"(hfr[kt]) : "v"(hp) : "memory");
    }

    f32x4 accv[4];
    #pragma unroll
    for (int c=0;c<4;++c) accv[c] = (f32x4){0.f,0.f,0.f,0.f};

    // first half: wait for the 16 oldest loads (hfr[0..15]), overlap tail with MFMA
    asm volatile("s_waitcnt vmcnt(16)" ::: "memory");
    __builtin_amdgcn_sched_barrier(0);
    #pragma unroll
    for (int kt=0; kt<16; ++kt){
      f16x8 a = *(const f16x8*)(Rlds + ((size_t)kt*64 + l)*8);
      accv[kt&3] = __builtin_amdgcn_mfma_f32_16x16x32_f16(a, hfr[kt], accv[kt&3], 0, 0, 0);
    }
    asm volatile("s_waitcnt vmcnt(0)" ::: "memory");
    __builtin_amdgcn_sched_barrier(0);

    // prefetch next step's wx/alpha (plain cached f16 loads; complete under 2nd MFMA half)
    int tn = (t+1 < TT) ? (t+1) : t;
    size_t offn = ((size_t)tn*BB + b)*DD + e0 + rr0;
    f16x4v whn = *(const f16x4v*)(wx + offn);
    f16x4v ahn = *(const f16x4v*)(alpha + offn);

    #pragma unroll
    for (int kt=16; kt<32; ++kt){
      f16x8 a = *(const f16x8*)(Rlds + ((size_t)kt*64 + l)*8);
      accv[kt&3] = __builtin_amdgcn_mfma_f32_16x16x32_f16(a, hfr[kt], accv[kt&3], 0, 0, 0);
    }
    f32x4 acc = (accv[0]+accv[1]) + (accv[2]+accv[3]);

    // pointwise epilogue (same wave; no reduce, no barrier)
    f16x4v h4;
    float hs[4] = {hstate.x, hstate.y, hstate.z, hstate.w};
    #pragma unroll
    for (int r=0;r<4;++r){
      float z = acc[r] + wxv[r];
      float cand = tanhf(z);
      float hn = alv[r]*hs[r] + (1.f - alv[r])*cand;
      hs[r] = hn;
      h4[r] = (f16)hn;
    }
    hstate = (float4){hs[0], hs[1], hs[2], hs[3]};

    // release: one 8B coherent store per lane -> drain -> lane0 publishes
    f16* hw = hbuf + (size_t)((t+1) & 1) * (BB*DD) + (size_t)b*DD + e0 + rr0;
    uint2v hv = __builtin_bit_cast(uint2v, h4);
    asm volatile("global_store_dwordx2 %0, %1, off sc0 sc1"
                 :: "v"(hw), "v"(hv) : "memory");
    asm volatile("s_waitcnt vmcnt(0)" ::: "memory");
    if (l == 0)
      __hip_atomic_store(flags + j*FPAD, (unsigned)(t+1),
                         __ATOMIC_RELAXED, __HIP_MEMORY_SCOPE_AGENT);

    // off the critical path: plain hout store, rotate wx/alpha
    *(f16x4v*)(hout + ((size_t)t*BB + b)*DD + e0 + rr0) = h4;
    #pragma unroll
    for (int r=0;r<4;++r){ wxv[r] = (float)whn[r]; alv[r] = (float)ahn[r]; }
  }
}

// ---------------- host launcher ----------------
extern "C" void kernel_launch(void* const* d_in, const int* in_sizes, int n_in,
                              void* d_out, int out_size, void* d_ws, size_t ws_size,
                              hipStream_t stream)
{
  const float* x    = (const float*)d_in[0];
  const float* h0   = (const float*)d_in[1];
  const float* Wx   = (const float*)d_in[2];
  const float* R    = (const float*)d_in[3];
  const float* bias = (const float*)d_in[4];
  const float* Wd   = (const float*)d_in[5];
  const float* bd   = (const float*)d_in[6];
  const float* Aar  = (const float*)d_in[7];
  const float* Wgx  = (const float*)d_in[8];
  const float* Wgh  = (const float*)d_in[9];
  const float* bg   = (const float*)d_in[10];
  float* out = (float*)d_out;

  char* ws = (char*)d_ws;
  size_t off = 0;
  auto carve = [&](size_t bytes) -> void* {
    void* p = ws + off;
    off += (bytes + 255) & ~(size_t)255;
    return p;
  };
  f16* x16    = (f16*)carve((size_t)MM*DD*2);
  f16* Wx16   = (f16*)carve((size_t)DD*DD*2);
  f16* Wd16   = (f16*)carve((size_t)DD*DD*2);
  f16* Wgx16  = (f16*)carve((size_t)DD*DD*2);
  f16* Wgh16  = (f16*)carve((size_t)DD*DD*2);
  f16* R16    = (f16*)carve((size_t)DD*DD*2);
  f16* wx16   = (f16*)carve((size_t)MM*DD*2);
  f16* al16   = (f16*)carve((size_t)MM*DD*2);
  f16* gx16   = (f16*)carve((size_t)MM*DD*2);
  f16* hout16 = (f16*)carve((size_t)MM*DD*2);
  f16* hbuf   = (f16*)carve((size_t)2*BB*DD*2);
  unsigned* flags = (unsigned*)carve(64*FPAD*4);
  if (off > ws_size) return;  // ws too small: leave d_out poisoned (visible failure)

  cvt_kernel<<<1024, 256, 0, stream>>>(x, x16, MM*DD/4);
  dim3 g5(DD*DD/4/256, 5);
  cvt5_kernel<<<g5, 256, 0, stream>>>(Wx, Wd, Wgx, Wgh, R,
                                      Wx16, Wd16, Wgx16, Wgh16, R16);
  init_rec_kernel<<<64, 256, 0, stream>>>(h0, hbuf, flags);

  dim3 gg(MM/128, DD/128);
  gemm_f16_kernel<<<gg, 256, 0, stream>>>(x16, Wx16,  nullptr, wx16, bias, nullptr, nullptr, 0);
  gemm_f16_kernel<<<gg, 256, 0, stream>>>(x16, Wd16,  nullptr, al16, bd,   Aar,     nullptr, 1);
  gemm_f16_kernel<<<gg, 256, 0, stream>>>(x16, Wgx16, nullptr, gx16, bg,   nullptr, nullptr, 2);

  rec_kernel<<<64, 64, 0, stream>>>(R16, wx16, al16, h0, hbuf, hout16, flags);

  gemm_f16_kernel<<<gg, 256, 0, stream>>>(hout16, Wgh16, out, nullptr, nullptr, nullptr, gx16, 3);
}

// Round 13
// 7092.423 us; speedup vs baseline: 1.5959x; 1.0264x over previous
//
#include <hip/hip_runtime.h>
#include <cstdint>
#include <cstddef>

typedef _Float16 f16;
typedef _Float16 f16x8 __attribute__((ext_vector_type(8)));
typedef _Float16 f16x4v __attribute__((ext_vector_type(4)));
typedef float f32x4 __attribute__((ext_vector_type(4)));
typedef unsigned uint2v __attribute__((ext_vector_type(2)));

#define TT 2048
#define BB 16
#define DD 1024
#define MM (TT*BB)
#define LDST 40   // padded LDS row stride (halves) to break bank conflicts
#define FPAD 16   // flag padding: one flag per 64B line

// ---------------- f32 -> f16 convert (single buffer) ----------------
__global__ void cvt_kernel(const float* __restrict__ in, f16* __restrict__ out, int n4){
  int stride = gridDim.x * blockDim.x;
  for (int j = blockIdx.x*blockDim.x + threadIdx.x; j < n4; j += stride){
    float4 v = ((const float4*)in)[j];
    f16x4v o;
    o[0]=(f16)v.x; o[1]=(f16)v.y; o[2]=(f16)v.z; o[3]=(f16)v.w;
    ((f16x4v*)out)[j] = o;
  }
}

// ---------------- fused f32->f16 convert for the 5 DxD weights ----------------
__global__ void cvt5_kernel(const float* __restrict__ a0, const float* __restrict__ a1,
                            const float* __restrict__ a2, const float* __restrict__ a3,
                            const float* __restrict__ a4,
                            f16* __restrict__ o0, f16* __restrict__ o1,
                            f16* __restrict__ o2, f16* __restrict__ o3, f16* __restrict__ o4){
  const float* src[5] = {a0,a1,a2,a3,a4};
  f16* dst[5] = {o0,o1,o2,o3,o4};
  int which = blockIdx.y;
  const float* in = src[which];
  f16* out = dst[which];
  int j = blockIdx.x*blockDim.x + threadIdx.x;
  float4 v = ((const float4*)in)[j];
  f16x4v o;
  o[0]=(f16)v.x; o[1]=(f16)v.y; o[2]=(f16)v.z; o[3]=(f16)v.w;
  ((f16x4v*)out)[j] = o;
}

// ---------------- recurrence init: zero flags, h0 -> hbuf[0] ----------------
__global__ void init_rec_kernel(const float* __restrict__ h0, f16* __restrict__ hbuf,
                                unsigned* __restrict__ flags){
  int tid = blockIdx.x*blockDim.x + threadIdx.x;
  if (tid < 64*FPAD) flags[tid] = 0u;
  if (tid < BB*DD) hbuf[tid] = (f16)h0[tid];
}

// ======== shared GEMM tile machinery (128x128, f16 MFMA, B given as [N,K]) ========
// Computes into acc[4][4]; A/B tile sources selected per K-tile by the caller lambda.
#define GEMM_PROLOGUE() \
  __shared__ f16 As[128*LDST]; \
  __shared__ f16 Bs[128*LDST]; \
  int tid = threadIdx.x; \
  int l = tid & 63, w = tid >> 6; \
  int wr = w >> 1, wc = w & 1; \
  f32x4 acc[4][4]; \
  _Pragma("unroll") for (int i=0;i<4;++i) _Pragma("unroll") for (int jj=0;jj<4;++jj) \
    acc[i][jj] = (f32x4){0.f,0.f,0.f,0.f}; \
  const int r0 = tid >> 2; \
  const int q  = tid & 3;

#define GEMM_KSTEP(Asrc, Bsrc, ktl) { \
  __syncthreads(); \
  _Pragma("unroll") for (int hh=0; hh<2; ++hh){ \
    int row = hh*64 + r0; \
    uint4 va = *(const uint4*)((Asrc) + (size_t)(bm*128+row)*DD + (ktl)*32 + q*8); \
    uint4 vb = *(const uint4*)((Bsrc) + (size_t)(bcol*128+row)*DD + (ktl)*32 + q*8); \
    *(uint4*)(As + row*LDST + q*8) = va; \
    *(uint4*)(Bs + row*LDST + q*8) = vb; \
  } \
  __syncthreads(); \
  int lr = l & 15, kg = (l >> 4) * 8; \
  f16x8 af[4], bf[4]; \
  _Pragma("unroll") for (int i=0;i<4;++i){ \
    af[i] = *(const f16x8*)(As + (wr*64 + i*16 + lr)*LDST + kg); \
    bf[i] = *(const f16x8*)(Bs + (wc*64 + i*16 + lr)*LDST + kg); \
  } \
  _Pragma("unroll") for (int i=0;i<4;++i) \
    _Pragma("unroll") for (int jj=0;jj<4;++jj) \
      acc[i][jj] = __builtin_amdgcn_mfma_f32_16x16x32_f16(af[i], bf[jj], acc[i][jj], 0,0,0); \
}

// ---------------- fused wx + alpha GEMM: grid (MM/128, 16) ----------------
// bn<8: wx = x@Wx^T + bias -> f16 ; bn>=8: alpha = exp(-softplus(x@Wd^T+bd)*exp(-exp(A))) -> f16
__global__ __launch_bounds__(256)
void gemm_wa_kernel(const f16* __restrict__ x16,
                    const f16* __restrict__ Wx16, const f16* __restrict__ Wd16,
                    f16* __restrict__ wxo, f16* __restrict__ alo,
                    const float* __restrict__ bias, const float* __restrict__ bd,
                    const float* __restrict__ Aar)
{
  int bm = blockIdx.x, bn = blockIdx.y;
  int alpha_path = (bn >= 8);
  int bcol = bn & 7;
  const f16* Bw = alpha_path ? Wd16 : Wx16;

  GEMM_PROLOGUE();
  for (int kt = 0; kt < 32; ++kt) GEMM_KSTEP(x16, Bw, kt);

  int lr = l & 15, lh = l >> 4;
  #pragma unroll
  for (int i=0;i<4;++i){
    #pragma unroll
    for (int jj=0;jj<4;++jj){
      #pragma unroll
      for (int r=0;r<4;++r){
        int row = bm*128 + wr*64 + i*16 + lh*4 + r;
        int col = bcol*128 + wc*64 + jj*16 + lr;
        float v = acc[i][jj][r];
        size_t off = (size_t)row*DD + col;
        if (!alpha_path){
          wxo[off] = (f16)(v + bias[col]);
        } else {
          float pre = v + bd[col];
          float sp  = (pre > 20.f) ? pre : log1pf(expf(pre));
          float decay = expf(-expf(Aar[col]));
          alo[off] = (f16)expf(-sp*decay);
        }
      }
    }
  }
}

// ---------------- fused final GEMM (K=2048): out = hout * silu(hout@Wgh^T + x@Wgx^T + bg) ----
__global__ __launch_bounds__(256)
void gemm_fin_kernel(const f16* __restrict__ hout16, const f16* __restrict__ x16,
                     const f16* __restrict__ Wgh16, const f16* __restrict__ Wgx16,
                     float* __restrict__ out, const float* __restrict__ bg)
{
  int bm = blockIdx.x, bcol = blockIdx.y;

  GEMM_PROLOGUE();
  for (int kt = 0; kt < 32; ++kt) GEMM_KSTEP(hout16, Wgh16, kt);
  for (int kt = 0; kt < 32; ++kt) GEMM_KSTEP(x16,    Wgx16, kt);

  int lr = l & 15, lh = l >> 4;
  #pragma unroll
  for (int i=0;i<4;++i){
    #pragma unroll
    for (int jj=0;jj<4;++jj){
      #pragma unroll
      for (int r=0;r<4;++r){
        int row = bm*128 + wr*64 + i*16 + lh*4 + r;
        int col = bcol*128 + wc*64 + jj*16 + lr;
        float g = acc[i][jj][r] + bg[col];
        size_t off = (size_t)row*DD + col;
        float hval = (float)hout16[off];
        out[off] = hval * g / (1.f + expf(-g));
      }
    }
  }
}

// ---------------- recurrence: 64 autonomous single-wave WGs (proven R8/R12 protocol) --------
// release = 8B sc0sc1 store/lane -> vmcnt(0) -> lane0 flag store (AGENT atomic);
// acquire = lane l polls flags[l*FPAD] until all >= t (ballot) -> sc0sc1 h loads.
// This round: 4-way vmcnt split (24/16/8/0) for finer h-load/MFMA overlap.
__global__ __launch_bounds__(64)
void rec_kernel(const f16* __restrict__ Rf, const f16* __restrict__ wx,
                const f16* __restrict__ alpha, const float* __restrict__ h0,
                f16* __restrict__ hbuf, f16* __restrict__ hout,
                unsigned* __restrict__ flags)
{
  __shared__ f16 Rlds[32*64*8];   // 32KB, frag-ordered: chunk c = kt*64+lane, 8 halves each

  int l = threadIdx.x;             // 0..63 (one wave per WG)
  int j = blockIdx.x;              // slice id 0..63
  int e0 = j * 16;

  #pragma unroll
  for (int kt=0; kt<32; ++kt){
    int e = e0 + (l & 15);
    int d = kt*32 + (l >> 4)*8;
    *(uint4*)(Rlds + ((size_t)kt*64 + l)*8) = *(const uint4*)(Rf + (size_t)e*DD + d);
  }

  int b = l & 15, rr0 = (l >> 4) * 4;
  float4 hstate = *(const float4*)(h0 + (size_t)b*DD + e0 + rr0);
  __syncthreads();

  f32x4 wxv, alv;
  {
    f16x4v wh = *(const f16x4v*)(wx + (size_t)b*DD + e0 + rr0);
    f16x4v ah = *(const f16x4v*)(alpha + (size_t)b*DD + e0 + rr0);
    #pragma unroll
    for (int r=0;r<4;++r){ wxv[r] = (float)wh[r]; alv[r] = (float)ah[r]; }
  }

  for (int t = 0; t < TT; ++t){
    if (t > 0){
      const unsigned* fp = flags + l*FPAD;
      int guard = 0;
      unsigned long long notready = 1ull;
      while (notready && guard < 2000000){
        unsigned fv = __hip_atomic_load(fp, __ATOMIC_RELAXED, __HIP_MEMORY_SCOPE_AGENT);
        notready = __ballot(fv < (unsigned)t);
        ++guard;
        if (notready) __builtin_amdgcn_s_sleep(1);
      }
    }

    // coherent single-shot load of this lane's full h K-slice (bypass stale caches)
    const f16* hb = hbuf + (size_t)(t & 1) * (BB*DD);
    f16x8 hfr[32];
    #pragma unroll
    for (int kt=0; kt<32; ++kt){
      const f16* hp = hb + (size_t)b*DD + kt*32 + (l >> 4)*8;
      asm volatile("global_load_dwordx4 %0, %1, off sc0 sc1"
                   : "=v"(hfr[kt]) : "v"(hp) : "memory");
    }

    f32x4 accv[4];
    #pragma unroll
    for (int c=0;c<4;++c) accv[c] = (f32x4){0.f,0.f,0.f,0.f};

    // 4-way split wait: overlap h-load tail with MFMA in 8-MFMA chunks
    asm volatile("s_waitcnt vmcnt(24)" ::: "memory");
    __builtin_amdgcn_sched_barrier(0);
    #pragma unroll
    for (int kt=0; kt<8; ++kt){
      f16x8 a = *(const f16x8*)(Rlds + ((size_t)kt*64 + l)*8);
      accv[kt&3] = __builtin_amdgcn_mfma_f32_16x16x32_f16(a, hfr[kt], accv[kt&3], 0, 0, 0);
    }
    asm volatile("s_waitcnt vmcnt(16)" ::: "memory");
    __builtin_amdgcn_sched_barrier(0);
    #pragma unroll
    for (int kt=8; kt<16; ++kt){
      f16x8 a = *(const f16x8*)(Rlds + ((size_t)kt*64 + l)*8);
      accv[kt&3] = __builtin_amdgcn_mfma_f32_16x16x32_f16(a, hfr[kt], accv[kt&3], 0, 0, 0);
    }
    asm volatile("s_waitcnt vmcnt(8)" ::: "memory");
    __builtin_amdgcn_sched_barrier(0);

    // prefetch next step's wx/alpha under the remaining MFMA work
    int tn = (t+1 < TT) ? (t+1) : t;
    size_t offn = ((size_t)tn*BB + b)*DD + e0 + rr0;
    f16x4v whn = *(const f16x4v*)(wx + offn);
    f16x4v ahn = *(const f16x4v*)(alpha + offn);

    #pragma unroll
    for (int kt=16; kt<24; ++kt){
      f16x8 a = *(const f16x8*)(Rlds + ((size_t)kt*64 + l)*8);
      accv[kt&3] = __builtin_amdgcn_mfma_f32_16x16x32_f16(a, hfr[kt], accv[kt&3], 0, 0, 0);
    }
    asm volatile("s_waitcnt vmcnt(0)" ::: "memory");
    __builtin_amdgcn_sched_barrier(0);
    #pragma unroll
    for (int kt=24; kt<32; ++kt){
      f16x8 a = *(const f16x8*)(Rlds + ((size_t)kt*64 + l)*8);
      accv[kt&3] = __builtin_amdgcn_mfma_f32_16x16x32_f16(a, hfr[kt], accv[kt&3], 0, 0, 0);
    }
    f32x4 acc = (accv[0]+accv[1]) + (accv[2]+accv[3]);

    // pointwise epilogue (same wave; no reduce, no barrier)
    f16x4v h4;
    float hs[4] = {hstate.x, hstate.y, hstate.z, hstate.w};
    #pragma unroll
    for (int r=0;r<4;++r){
      float z = acc[r] + wxv[r];
      float cand = tanhf(z);
      float hn = alv[r]*hs[r] + (1.f - alv[r])*cand;
      hs[r] = hn;
      h4[r] = (f16)hn;
    }
    hstate = (float4){hs[0], hs[1], hs[2], hs[3]};

    // release: one 8B coherent store per lane -> drain -> lane0 publishes
    f16* hw = hbuf + (size_t)((t+1) & 1) * (BB*DD) + (size_t)b*DD + e0 + rr0;
    uint2v hv = __builtin_bit_cast(uint2v, h4);
    asm volatile("global_store_dwordx2 %0, %1, off sc0 sc1"
                 :: "v"(hw), "v"(hv) : "memory");
    asm volatile("s_waitcnt vmcnt(0)" ::: "memory");
    if (l == 0)
      __hip_atomic_store(flags + j*FPAD, (unsigned)(t+1),
                         __ATOMIC_RELAXED, __HIP_MEMORY_SCOPE_AGENT);

    // off the critical path: plain hout store, rotate wx/alpha
    *(f16x4v*)(hout + ((size_t)t*BB + b)*DD + e0 + rr0) = h4;
    #pragma unroll
    for (int r=0;r<4;++r){ wxv[r] = (float)whn[r]; alv[r] = (float)ahn[r]; }
  }
}

// ---------------- host launcher ----------------
extern "C" void kernel_launch(void* const* d_in, const int* in_sizes, int n_in,
                              void* d_out, int out_size, void* d_ws, size_t ws_size,
                              hipStream_t stream)
{
  const float* x    = (const float*)d_in[0];
  const float* h0   = (const float*)d_in[1];
  const float* Wx   = (const float*)d_in[2];
  const float* R    = (const float*)d_in[3];
  const float* bias = (const float*)d_in[4];
  const float* Wd   = (const float*)d_in[5];
  const float* bd   = (const float*)d_in[6];
  const float* Aar  = (const float*)d_in[7];
  const float* Wgx  = (const float*)d_in[8];
  const float* Wgh  = (const float*)d_in[9];
  const float* bg   = (const float*)d_in[10];
  float* out = (float*)d_out;

  char* ws = (char*)d_ws;
  size_t off = 0;
  auto carve = [&](size_t bytes) -> void* {
    void* p = ws + off;
    off += (bytes + 255) & ~(size_t)255;
    return p;
  };
  f16* x16    = (f16*)carve((size_t)MM*DD*2);
  f16* Wx16   = (f16*)carve((size_t)DD*DD*2);
  f16* Wd16   = (f16*)carve((size_t)DD*DD*2);
  f16* Wgx16  = (f16*)carve((size_t)DD*DD*2);
  f16* Wgh16  = (f16*)carve((size_t)DD*DD*2);
  f16* R16    = (f16*)carve((size_t)DD*DD*2);
  f16* wx16   = (f16*)carve((size_t)MM*DD*2);
  f16* al16   = (f16*)carve((size_t)MM*DD*2);
  f16* hout16 = (f16*)carve((size_t)MM*DD*2);
  f16* hbuf   = (f16*)carve((size_t)2*BB*DD*2);
  unsigned* flags = (unsigned*)carve(64*FPAD*4);
  if (off > ws_size) return;

  cvt_kernel<<<1024, 256, 0, stream>>>(x, x16, MM*DD/4);
  dim3 g5(DD*DD/4/256, 5);
  cvt5_kernel<<<g5, 256, 0, stream>>>(Wx, Wd, Wgx, Wgh, R,
                                      Wx16, Wd16, Wgx16, Wgh16, R16);
  init_rec_kernel<<<64, 256, 0, stream>>>(h0, hbuf, flags);

  dim3 gwa(MM/128, 16);
  gemm_wa_kernel<<<gwa, 256, 0, stream>>>(x16, Wx16, Wd16, wx16, al16, bias, bd, Aar);

  rec_kernel<<<64, 64, 0, stream>>>(R16, wx16, al16, h0, hbuf, hout16, flags);

  dim3 gfin(MM/128, DD/128);
  gemm_fin_kernel<<<gfin, 256, 0, stream>>>(hout16, x16, Wgh16, Wgx16, out, bg);
}

// Round 14
// 7008.595 us; speedup vs baseline: 1.6150x; 1.0120x over previous
//
#include <hip/hip_runtime.h>
#include <cstdint>
#include <cstddef>

typedef _Float16 f16;
typedef _Float16 f16x8 __attribute__((ext_vector_type(8)));
typedef _Float16 f16x4v __attribute__((ext_vector_type(4)));
typedef float f32x4 __attribute__((ext_vector_type(4)));
typedef unsigned uint2v __attribute__((ext_vector_type(2)));

#define TT 2048
#define BB 16
#define DD 1024
#define MM (TT*BB)
#define FPAD 16   // flag padding: one flag per 64B line

// ---------------- f32 -> f16 convert (single buffer) ----------------
__global__ void cvt_kernel(const float* __restrict__ in, f16* __restrict__ out, int n4){
  int stride = gridDim.x * blockDim.x;
  for (int j = blockIdx.x*blockDim.x + threadIdx.x; j < n4; j += stride){
    float4 v = ((const float4*)in)[j];
    f16x4v o;
    o[0]=(f16)v.x; o[1]=(f16)v.y; o[2]=(f16)v.z; o[3]=(f16)v.w;
    ((f16x4v*)out)[j] = o;
  }
}

// ---------------- fused f32->f16 convert for the 5 DxD weights ----------------
__global__ void cvt5_kernel(const float* __restrict__ a0, const float* __restrict__ a1,
                            const float* __restrict__ a2, const float* __restrict__ a3,
                            const float* __restrict__ a4,
                            f16* __restrict__ o0, f16* __restrict__ o1,
                            f16* __restrict__ o2, f16* __restrict__ o3, f16* __restrict__ o4){
  const float* src[5] = {a0,a1,a2,a3,a4};
  f16* dst[5] = {o0,o1,o2,o3,o4};
  int which = blockIdx.y;
  const float* in = src[which];
  f16* out = dst[which];
  int j = blockIdx.x*blockDim.x + threadIdx.x;
  float4 v = ((const float4*)in)[j];
  f16x4v o;
  o[0]=(f16)v.x; o[1]=(f16)v.y; o[2]=(f16)v.z; o[3]=(f16)v.w;
  ((f16x4v*)out)[j] = o;
}

// ---------------- recurrence init: zero flags, h0 -> hbuf[0] ----------------
__global__ void init_rec_kernel(const float* __restrict__ h0, f16* __restrict__ hbuf,
                                unsigned* __restrict__ flags){
  int tid = blockIdx.x*blockDim.x + threadIdx.x;
  if (tid < 64*FPAD) flags[tid] = 0u;
  if (tid < BB*DD) hbuf[tid] = (f16)h0[tid];
}

// ======== shared GEMM tile machinery (128x128, f16 MFMA, B given as [N,K]) ========
// Staging: global_load_lds width=16, LINEAR LDS dest (tid*16B), chunk-XOR swizzle applied
// on BOTH sides (rule #21): global chunk q = c ^ (r&3) feeds stored chunk c; fragment
// reads use stored chunk (g ^ (row&3)). Tile = 128 rows x 32 halves = 8KB, 2 issues/thread.
#define GEMM_PROLOGUE() \
  __shared__ f16 As[128*32]; \
  __shared__ f16 Bs[128*32]; \
  int tid = threadIdx.x; \
  int l = tid & 63, w = tid >> 6; \
  int wr = w >> 1, wc = w & 1; \
  f32x4 acc[4][4]; \
  _Pragma("unroll") for (int i=0;i<4;++i) _Pragma("unroll") for (int jj=0;jj<4;++jj) \
    acc[i][jj] = (f32x4){0.f,0.f,0.f,0.f};

#define GEMM_KSTEP(Asrc, Bsrc, ktl) { \
  __syncthreads(); \
  _Pragma("unroll") for (int hh=0; hh<2; ++hh){ \
    int r = hh*64 + (tid>>2); \
    int q = (tid&3) ^ (r&3); \
    const f16* ga = (Asrc) + (size_t)(bm*128+r)*DD + (ktl)*32 + q*8; \
    const f16* gb = (Bsrc) + (size_t)(bcol*128+r)*DD + (ktl)*32 + q*8; \
    __builtin_amdgcn_global_load_lds((__attribute__((address_space(1))) void*)ga, \
        (__attribute__((address_space(3))) void*)(As + hh*2048 + tid*8), 16, 0, 0); \
    __builtin_amdgcn_global_load_lds((__attribute__((address_space(1))) void*)gb, \
        (__attribute__((address_space(3))) void*)(Bs + hh*2048 + tid*8), 16, 0, 0); \
  } \
  __syncthreads(); \
  int lr = l & 15, g = l >> 4; \
  f16x8 af[4], bf[4]; \
  _Pragma("unroll") for (int i=0;i<4;++i){ \
    int Ra = wr*64 + i*16 + lr; \
    int Rb = wc*64 + i*16 + lr; \
    af[i] = *(const f16x8*)(As + Ra*32 + ((g ^ (Ra & 3)) * 8)); \
    bf[i] = *(const f16x8*)(Bs + Rb*32 + ((g ^ (Rb & 3)) * 8)); \
  } \
  _Pragma("unroll") for (int i=0;i<4;++i) \
    _Pragma("unroll") for (int jj=0;jj<4;++jj) \
      acc[i][jj] = __builtin_amdgcn_mfma_f32_16x16x32_f16(af[i], bf[jj], acc[i][jj], 0,0,0); \
}

// ---------------- fused wx + alpha GEMM: grid (MM/128, 16) ----------------
// bn<8: wx = x@Wx^T + bias -> f16 ; bn>=8: alpha = exp(-softplus(x@Wd^T+bd)*exp(-exp(A))) -> f16
__global__ __launch_bounds__(256)
void gemm_wa_kernel(const f16* __restrict__ x16,
                    const f16* __restrict__ Wx16, const f16* __restrict__ Wd16,
                    f16* __restrict__ wxo, f16* __restrict__ alo,
                    const float* __restrict__ bias, const float* __restrict__ bd,
                    const float* __restrict__ Aar)
{
  int bm = blockIdx.x, bn = blockIdx.y;
  int alpha_path = (bn >= 8);
  int bcol = bn & 7;
  const f16* Bw = alpha_path ? Wd16 : Wx16;

  GEMM_PROLOGUE();
  for (int kt = 0; kt < 32; ++kt) GEMM_KSTEP(x16, Bw, kt);

  int lr = l & 15, lh = l >> 4;
  #pragma unroll
  for (int i=0;i<4;++i){
    #pragma unroll
    for (int jj=0;jj<4;++jj){
      #pragma unroll
      for (int r=0;r<4;++r){
        int row = bm*128 + wr*64 + i*16 + lh*4 + r;
        int col = bcol*128 + wc*64 + jj*16 + lr;
        float v = acc[i][jj][r];
        size_t off = (size_t)row*DD + col;
        if (!alpha_path){
          wxo[off] = (f16)(v + bias[col]);
        } else {
          float pre = v + bd[col];
          float sp  = (pre > 20.f) ? pre : log1pf(expf(pre));
          float decay = expf(-expf(Aar[col]));
          alo[off] = (f16)expf(-sp*decay);
        }
      }
    }
  }
}

// ---------------- fused final GEMM (K=2048): out = hout * silu(hout@Wgh^T + x@Wgx^T + bg) ----
__global__ __launch_bounds__(256)
void gemm_fin_kernel(const f16* __restrict__ hout16, const f16* __restrict__ x16,
                     const f16* __restrict__ Wgh16, const f16* __restrict__ Wgx16,
                     float* __restrict__ out, const float* __restrict__ bg)
{
  int bm = blockIdx.x, bcol = blockIdx.y;

  GEMM_PROLOGUE();
  for (int kt = 0; kt < 32; ++kt) GEMM_KSTEP(hout16, Wgh16, kt);
  for (int kt = 0; kt < 32; ++kt) GEMM_KSTEP(x16,    Wgx16, kt);

  int lr = l & 15, lh = l >> 4;
  #pragma unroll
  for (int i=0;i<4;++i){
    #pragma unroll
    for (int jj=0;jj<4;++jj){
      #pragma unroll
      for (int r=0;r<4;++r){
        int row = bm*128 + wr*64 + i*16 + lh*4 + r;
        int col = bcol*128 + wc*64 + jj*16 + lr;
        float g = acc[i][jj][r] + bg[col];
        size_t off = (size_t)row*DD + col;
        float hval = (float)hout16[off];
        out[off] = hval * g / (1.f + expf(-g));
      }
    }
  }
}

// ---------------- recurrence: 64 autonomous single-wave WGs (proven R8/R12/R13 protocol) ----
// release = 8B sc0sc1 store/lane -> vmcnt(0) -> lane0 flag store (AGENT atomic);
// acquire = lane l polls flags[l*FPAD] until all >= t (ballot) -> sc0sc1 h loads.
// Only change this round: hot-spin the first 16 polls (s_sleep only after).
__global__ __launch_bounds__(64)
void rec_kernel(const f16* __restrict__ Rf, const f16* __restrict__ wx,
                const f16* __restrict__ alpha, const float* __restrict__ h0,
                f16* __restrict__ hbuf, f16* __restrict__ hout,
                unsigned* __restrict__ flags)
{
  __shared__ f16 Rlds[32*64*8];   // 32KB, frag-ordered: chunk c = kt*64+lane, 8 halves each

  int l = threadIdx.x;             // 0..63 (one wave per WG)
  int j = blockIdx.x;              // slice id 0..63
  int e0 = j * 16;

  #pragma unroll
  for (int kt=0; kt<32; ++kt){
    int e = e0 + (l & 15);
    int d = kt*32 + (l >> 4)*8;
    *(uint4*)(Rlds + ((size_t)kt*64 + l)*8) = *(const uint4*)(Rf + (size_t)e*DD + d);
  }

  int b = l & 15, rr0 = (l >> 4) * 4;
  float4 hstate = *(const float4*)(h0 + (size_t)b*DD + e0 + rr0);
  __syncthreads();

  f32x4 wxv, alv;
  {
    f16x4v wh = *(const f16x4v*)(wx + (size_t)b*DD + e0 + rr0);
    f16x4v ah = *(const f16x4v*)(alpha + (size_t)b*DD + e0 + rr0);
    #pragma unroll
    for (int r=0;r<4;++r){ wxv[r] = (float)wh[r]; alv[r] = (float)ah[r]; }
  }

  for (int t = 0; t < TT; ++t){
    if (t > 0){
      const unsigned* fp = flags + l*FPAD;
      int guard = 0;
      unsigned long long notready = 1ull;
      while (notready && guard < 2000000){
        unsigned fv = __hip_atomic_load(fp, __ATOMIC_RELAXED, __HIP_MEMORY_SCOPE_AGENT);
        notready = __ballot(fv < (unsigned)t);
        ++guard;
        if (notready && guard > 16) __builtin_amdgcn_s_sleep(1);
      }
    }

    // coherent single-shot load of this lane's full h K-slice (bypass stale caches)
    const f16* hb = hbuf + (size_t)(t & 1) * (BB*DD);
    f16x8 hfr[32];
    #pragma unroll
    for (int kt=0; kt<32; ++kt){
      const f16* hp = hb + (size_t)b*DD + kt*32 + (l >> 4)*8;
      asm volatile("global_load_dwordx4 %0, %1, off sc0 sc1"
                   : "=v"(hfr[kt]) : "v"(hp) : "memory");
    }

    f32x4 accv[4];
    #pragma unroll
    for (int c=0;c<4;++c) accv[c] = (f32x4){0.f,0.f,0.f,0.f};

    // 4-way split wait: overlap h-load tail with MFMA in 8-MFMA chunks
    asm volatile("s_waitcnt vmcnt(24)" ::: "memory");
    __builtin_amdgcn_sched_barrier(0);
    #pragma unroll
    for (int kt=0; kt<8; ++kt){
      f16x8 a = *(const f16x8*)(Rlds + ((size_t)kt*64 + l)*8);
      accv[kt&3] = __builtin_amdgcn_mfma_f32_16x16x32_f16(a, hfr[kt], accv[kt&3], 0, 0, 0);
    }
    asm volatile("s_waitcnt vmcnt(16)" ::: "memory");
    __builtin_amdgcn_sched_barrier(0);
    #pragma unroll
    for (int kt=8; kt<16; ++kt){
      f16x8 a = *(const f16x8*)(Rlds + ((size_t)kt*64 + l)*8);
      accv[kt&3] = __builtin_amdgcn_mfma_f32_16x16x32_f16(a, hfr[kt], accv[kt&3], 0, 0, 0);
    }
    asm volatile("s_waitcnt vmcnt(8)" ::: "memory");
    __builtin_amdgcn_sched_barrier(0);

    // prefetch next step's wx/alpha under the remaining MFMA work
    int tn = (t+1 < TT) ? (t+1) : t;
    size_t offn = ((size_t)tn*BB + b)*DD + e0 + rr0;
    f16x4v whn = *(const f16x4v*)(wx + offn);
    f16x4v ahn = *(const f16x4v*)(alpha + offn);

    #pragma unroll
    for (int kt=16; kt<24; ++kt){
      f16x8 a = *(const f16x8*)(Rlds + ((size_t)kt*64 + l)*8);
      accv[kt&3] = __builtin_amdgcn_mfma_f32_16x16x32_f16(a, hfr[kt], accv[kt&3], 0, 0, 0);
    }
    asm volatile("s_waitcnt vmcnt(0)" ::: "memory");
    __builtin_amdgcn_sched_barrier(0);
    #pragma unroll
    for (int kt=24; kt<32; ++kt){
      f16x8 a = *(const f16x8*)(Rlds + ((size_t)kt*64 + l)*8);
      accv[kt&3] = __builtin_amdgcn_mfma_f32_16x16x32_f16(a, hfr[kt], accv[kt&3], 0, 0, 0);
    }
    f32x4 acc = (accv[0]+accv[1]) + (accv[2]+accv[3]);

    // pointwise epilogue (same wave; no reduce, no barrier)
    f16x4v h4;
    float hs[4] = {hstate.x, hstate.y, hstate.z, hstate.w};
    #pragma unroll
    for (int r=0;r<4;++r){
      float z = acc[r] + wxv[r];
      float cand = tanhf(z);
      float hn = alv[r]*hs[r] + (1.f - alv[r])*cand;
      hs[r] = hn;
      h4[r] = (f16)hn;
    }
    hstate = (float4){hs[0], hs[1], hs[2], hs[3]};

    // release: one 8B coherent store per lane -> drain -> lane0 publishes
    f16* hw = hbuf + (size_t)((t+1) & 1) * (BB*DD) + (size_t)b*DD + e0 + rr0;
    uint2v hv = __builtin_bit_cast(uint2v, h4);
    asm volatile("global_store_dwordx2 %0, %1, off sc0 sc1"
                 :: "v"(hw), "v"(hv) : "memory");
    asm volatile("s_waitcnt vmcnt(0)" ::: "memory");
    if (l == 0)
      __hip_atomic_store(flags + j*FPAD, (unsigned)(t+1),
                         __ATOMIC_RELAXED, __HIP_MEMORY_SCOPE_AGENT);

    // off the critical path: plain hout store, rotate wx/alpha
    *(f16x4v*)(hout + ((size_t)t*BB + b)*DD + e0 + rr0) = h4;
    #pragma unroll
    for (int r=0;r<4;++r){ wxv[r] = (float)whn[r]; alv[r] = (float)ahn[r]; }
  }
}

// ---------------- host launcher ----------------
extern "C" void kernel_launch(void* const* d_in, const int* in_sizes, int n_in,
                              void* d_out, int out_size, void* d_ws, size_t ws_size,
                              hipStream_t stream)
{
  const float* x    = (const float*)d_in[0];
  const float* h0   = (const float*)d_in[1];
  const float* Wx   = (const float*)d_in[2];
  const float* R    = (const float*)d_in[3];
  const float* bias = (const float*)d_in[4];
  const float* Wd   = (const float*)d_in[5];
  const float* bd   = (const float*)d_in[6];
  const float* Aar  = (const float*)d_in[7];
  const float* Wgx  = (const float*)d_in[8];
  const float* Wgh  = (const float*)d_in[9];
  const float* bg   = (const float*)d_in[10];
  float* out = (float*)d_out;

  char* ws = (char*)d_ws;
  size_t off = 0;
  auto carve = [&](size_t bytes) -> void* {
    void* p = ws + off;
    off += (bytes + 255) & ~(size_t)255;
    return p;
  };
  f16* x16    = (f16*)carve((size_t)MM*DD*2);
  f16* Wx16   = (f16*)carve((size_t)DD*DD*2);
  f16* Wd16   = (f16*)carve((size_t)DD*DD*2);
  f16* Wgx16  = (f16*)carve((size_t)DD*DD*2);
  f16* Wgh16  = (f16*)carve((size_t)DD*DD*2);
  f16* R16    = (f16*)carve((size_t)DD*DD*2);
  f16* wx16   = (f16*)carve((size_t)MM*DD*2);
  f16* al16   = (f16*)carve((size_t)MM*DD*2);
  f16* hout16 = (f16*)carve((size_t)MM*DD*2);
  f16* hbuf   = (f16*)carve((size_t)2*BB*DD*2);
  unsigned* flags = (unsigned*)carve(64*FPAD*4);
  if (off > ws_size) return;

  cvt_kernel<<<1024, 256, 0, stream>>>(x, x16, MM*DD/4);
  dim3 g5(DD*DD/4/256, 5);
  cvt5_kernel<<<g5, 256, 0, stream>>>(Wx, Wd, Wgx, Wgh, R,
                                      Wx16, Wd16, Wgx16, Wgh16, R16);
  init_rec_kernel<<<64, 256, 0, stream>>>(h0, hbuf, flags);

  dim3 gwa(MM/128, 16);
  gemm_wa_kernel<<<gwa, 256, 0, stream>>>(x16, Wx16, Wd16, wx16, al16, bias, bd, Aar);

  rec_kernel<<<64, 64, 0, stream>>>(R16, wx16, al16, h0, hbuf, hout16, flags);

  dim3 gfin(MM/128, DD/128);
  gemm_fin_kernel<<<gfin, 256, 0, stream>>>(hout16, x16, Wgh16, Wgx16, out, bg);
}